// Round 5
// baseline (452.378 us; speedup 1.0000x reference)
//
#include <hip/hip_runtime.h>

// Problem constants
static constexpr int Bb = 8, Nn = 16384, Cc = 256, KO = 48, KK = 16;
static constexpr int RS = 264;   // LDS row stride in ushorts (256 + 8 pad -> bank skew 4/row)
#define EPSBN 1e-5f

typedef short bf16x8 __attribute__((ext_vector_type(8)));
typedef float f32x4 __attribute__((ext_vector_type(4)));
typedef unsigned short u16x4 __attribute__((ext_vector_type(4)));
typedef unsigned short u16x8 __attribute__((ext_vector_type(8)));

__device__ __forceinline__ unsigned short f2bf(float f) {
  unsigned u = __builtin_bit_cast(unsigned, f);
  u += 0x7FFFu + ((u >> 16) & 1u);   // round-to-nearest-even
  return (unsigned short)(u >> 16);
}

// ---------------------------------------------------------------------------
// prep: weights fp32 -> bf16 in MFMA-fragment-major (swizzled) order.
// Tile (rt, kt) of (16 out-ch x 32 k) stored as 512 contiguous ushorts:
// lane = (r%16) | ((k%32)/8)<<4 ; j = k%8 ; offset = tile*512 + lane*8 + j.
// ---------------------------------------------------------------------------
__global__ void prep_k(const float* __restrict__ W1, const float* __restrict__ W2,
                       const float* __restrict__ W3, const float* __restrict__ Wo,
                       const float* __restrict__ g1, const float* __restrict__ bb1,
                       const float* __restrict__ m1, const float* __restrict__ v1,
                       const float* __restrict__ g2, const float* __restrict__ bb2,
                       const float* __restrict__ m2, const float* __restrict__ v2,
                       const float* __restrict__ g3, const float* __restrict__ bb3,
                       const float* __restrict__ m3, const float* __restrict__ v3,
                       unsigned short* __restrict__ W1b, unsigned short* __restrict__ W2b,
                       unsigned short* __restrict__ W3b, unsigned short* __restrict__ Wob,
                       float* __restrict__ st1, float* __restrict__ st2,
                       float* __restrict__ st3) {
  int gid = blockIdx.x * 256 + threadIdx.x;
  if (gid < 65536) {
    int r = gid >> 8, k = gid & 255;
    int dst = (((r >> 4) * 8 + (k >> 5)) << 9) + (((r & 15) | (((k >> 3) & 3) << 4)) << 3) + (k & 7);
    W1b[dst] = f2bf(W1[gid]);
  } else if (gid < 131072) {
    int g = gid - 65536;
    int r = g >> 8, k = g & 255;
    int dst = (((r >> 4) * 8 + (k >> 5)) << 9) + (((r & 15) | (((k >> 3) & 3) << 4)) << 3) + (k & 7);
    W2b[dst] = f2bf(W2[g]);
  } else if (gid < 262144) {
    int g = gid - 131072;
    int r = g >> 8, k = g & 255;           // r in [0,512)
    int h = r >> 8, rr = r & 255;
    int dst = h * 65536 + ((((rr >> 4) * 8 + (k >> 5))) << 9) +
              (((rr & 15) | (((k >> 3) & 3) << 4)) << 3) + (k & 7);
    W3b[dst] = f2bf(W3[g]);
  } else if (gid < 286720) {
    int g = gid - 262144;
    int r = g >> 9, k = g & 511;           // Wo is 48 x 512
    int dst = (((r >> 4) * 16 + (k >> 5)) << 9) + (((r & 15) | (((k >> 3) & 3) << 4)) << 3) + (k & 7);
    Wob[dst] = f2bf(Wo[g]);
  }
  if (gid < 256) {
    float s = g1[gid] * rsqrtf(v1[gid] + EPSBN);
    st1[2 * gid] = s; st1[2 * gid + 1] = bb1[gid] - m1[gid] * s;
  } else if (gid < 512) {
    int i = gid - 256;
    float s = g2[i] * rsqrtf(v2[i] + EPSBN);
    st2[2 * i] = s; st2[2 * i + 1] = bb2[i] - m2[i] * s;
  } else if (gid < 1024) {
    int i = gid - 512;
    float s = g3[i] * rsqrtf(v3[i] + EPSBN);
    st3[2 * i] = s; st3[2 * i + 1] = bb3[i] - m3[i] * s;
  }
}

// ---------------------------------------------------------------------------
// backbone: 512 threads (8 waves), 128 points/block.
// Wave tile: 64 out-ch x 64 pts (cg = wave&3 ch-group, pg = wave>>2 pt-group)
// -> each wave reads only its 64 LDS rows (halved LDS read traffic).
// LDS: row-major [128][RS=264] ushorts; row stride 528B = bank skew 4.
// A (weights) from global (L2-hot), cur/nxt double-buffered 1 kb-step ahead.
// ---------------------------------------------------------------------------
__device__ __forceinline__ void gemm512(const unsigned short* __restrict__ src,
                                        unsigned short* __restrict__ dst,
                                        const unsigned short* __restrict__ Wsw,
                                        const float* __restrict__ st, int tid) {
  const int lane = tid & 63;
  const int wave = tid >> 6;
  const int cg = wave & 3;        // ch-group: 64 ch
  const int pg = wave >> 2;       // pt-group: 64 pts
  const int ln15 = lane & 15;
  const int q = lane >> 4;
  f32x4 acc[4][4] = {};
  const unsigned short* wb = Wsw + ((cg * 32) << 9) + lane * 8;

  bf16x8 a0[4], a1[4], b0[4], b1[4];
#pragma unroll
  for (int ct = 0; ct < 4; ++ct)
    a0[ct] = *reinterpret_cast<const bf16x8*>(wb + ((ct * 8) << 9));
#pragma unroll
  for (int pt = 0; pt < 4; ++pt)
    b0[pt] = *reinterpret_cast<const bf16x8*>(&src[(pg * 64 + pt * 16 + ln15) * RS + q * 8]);

#pragma unroll
  for (int kb = 0; kb < 8; ++kb) {
    const bf16x8* ac = (kb & 1) ? a1 : a0;
    const bf16x8* bc = (kb & 1) ? b1 : b0;
    bf16x8* an = (kb & 1) ? a0 : a1;
    bf16x8* bn = (kb & 1) ? b0 : b1;
    if (kb < 7) {
#pragma unroll
      for (int ct = 0; ct < 4; ++ct)
        an[ct] = *reinterpret_cast<const bf16x8*>(wb + ((ct * 8 + kb + 1) << 9));
#pragma unroll
      for (int pt = 0; pt < 4; ++pt)
        bn[pt] = *reinterpret_cast<const bf16x8*>(&src[(pg * 64 + pt * 16 + ln15) * RS + (kb + 1) * 32 + q * 8]);
    }
#pragma unroll
    for (int ct = 0; ct < 4; ++ct)
#pragma unroll
      for (int pt = 0; pt < 4; ++pt)
        acc[ct][pt] = __builtin_amdgcn_mfma_f32_16x16x32_bf16(ac[ct], bc[pt], acc[ct][pt], 0, 0, 0);
  }
  // epilogue: BN + ReLU, fp32 -> bf16, row-major LDS write (u16x4, 8B aligned)
#pragma unroll
  for (int ct = 0; ct < 4; ++ct) {
    const int chl = cg * 64 + ct * 16 + q * 4;
    float s0[4], t0[4];
#pragma unroll
    for (int r = 0; r < 4; ++r) {
      s0[r] = st[2 * (chl + r)];
      t0[r] = st[2 * (chl + r) + 1];
    }
#pragma unroll
    for (int pt = 0; pt < 4; ++pt) {
      const int p = pg * 64 + pt * 16 + ln15;
      u16x4 hv;
#pragma unroll
      for (int r = 0; r < 4; ++r) {
        float v = fmaxf(acc[ct][pt][r] * s0[r] + t0[r], 0.f);
        hv[r] = f2bf(v);
      }
      *reinterpret_cast<u16x4*>(&dst[p * RS + chl]) = hv;
    }
  }
}

// Wo partial: wave owns 16 points (8 waves x 16 = 128), all 48 output rows.
__device__ __forceinline__ void wo512(const unsigned short* __restrict__ src,
                                      const unsigned short* __restrict__ Wosw,
                                      int h, f32x4* accO, int tid) {
  const int lane = tid & 63;
  const int wave = tid >> 6;
  const int ln15 = lane & 15;
  const int q = lane >> 4;
#pragma unroll
  for (int kb = 0; kb < 8; ++kb) {
    bf16x8 bfr = *reinterpret_cast<const bf16x8*>(&src[(wave * 16 + ln15) * RS + kb * 32 + q * 8]);
#pragma unroll
    for (int ot = 0; ot < 3; ++ot) {
      bf16x8 afr = *reinterpret_cast<const bf16x8*>(&Wosw[((ot * 16 + 8 * h + kb) << 9) + lane * 8]);
      accO[ot] = __builtin_amdgcn_mfma_f32_16x16x32_bf16(afr, bfr, accO[ot], 0, 0, 0);
    }
  }
}

__global__ __launch_bounds__(512, 1) void backbone_k(
    const float* __restrict__ ff, const float* __restrict__ xyz,
    const unsigned short* __restrict__ W1b, const unsigned short* __restrict__ W2b,
    const unsigned short* __restrict__ W3b, const unsigned short* __restrict__ Wob,
    const float* __restrict__ st1, const float* __restrict__ st2,
    const float* __restrict__ st3, const float* __restrict__ bo,
    float* __restrict__ voted_t, float* __restrict__ block_part) {
  __shared__ unsigned short bufA[128 * RS];
  __shared__ unsigned short bufB[128 * RS];
  __shared__ float sh_part[8][KO];
  const int tid = threadIdx.x;
  const int b = blockIdx.x >> 7;
  const int n0 = (blockIdx.x & 127) * 128;
  const int lane = tid & 63;
  const int wave = tid >> 6;

  // stage ff tile -> bufA: thread handles 8 consecutive channels -> one b128
  // LDS write per iter. Rows advance with lane -> 2-way-min banking.
  {
    const float* src = ff + (size_t)(b * Nn + n0) * Cc;
    const int c8 = tid >> 4;        // 0..31 (x8 ch)
#pragma unroll
    for (int i = 0; i < 8; ++i) {
      int p = i * 16 + (tid & 15);
      const float* s = src + p * Cc + c8 * 8;
      const float4 v0 = *reinterpret_cast<const float4*>(s);
      const float4 v1 = *reinterpret_cast<const float4*>(s + 4);
      u16x8 h;
      h[0] = f2bf(v0.x); h[1] = f2bf(v0.y); h[2] = f2bf(v0.z); h[3] = f2bf(v0.w);
      h[4] = f2bf(v1.x); h[5] = f2bf(v1.y); h[6] = f2bf(v1.z); h[7] = f2bf(v1.w);
      *reinterpret_cast<u16x8*>(&bufA[p * RS + c8 * 8]) = h;
    }
  }
  __syncthreads();

  gemm512(bufA, bufB, W1b, st1, tid);
  __syncthreads();
  gemm512(bufB, bufA, W2b, st2, tid);
  __syncthreads();
  gemm512(bufA, bufB, W3b, st3, tid);
  __syncthreads();

  f32x4 accO[3] = {};
  wo512(bufB, Wob, 0, accO, tid);
  __syncthreads();
  gemm512(bufA, bufB, W3b + 65536, st3 + 512, tid);
  __syncthreads();
  wo512(bufB, Wob, 1, accO, tid);

  // epilogue: voted (transposed [b][o][n]) + block partial sums
  const int ln15 = lane & 15;
  const int q = lane >> 4;
  const int p = wave * 16 + ln15;
  const int n = n0 + p;
  const float* xp = xyz + (size_t)(b * Nn + n) * 3;
  float xv[3] = {xp[0], xp[1], xp[2]};
#pragma unroll
  for (int ot = 0; ot < 3; ++ot) {
#pragma unroll
    for (int r = 0; r < 4; ++r) {
      int o = ot * 16 + q * 4 + r;  // o = k*3 + d
      float v = accO[ot][r] + bo[o] + xv[o % 3];
      voted_t[(((size_t)b * KO + o) << 14) + n] = v;
      float s = v;
      s += __shfl_xor(s, 1, 64);
      s += __shfl_xor(s, 2, 64);
      s += __shfl_xor(s, 4, 64);
      s += __shfl_xor(s, 8, 64);
      if (ln15 == 0) sh_part[wave][o] = s;
    }
  }
  __syncthreads();
  if (tid < KO) {
    float t = 0.f;
#pragma unroll
    for (int w = 0; w < 8; ++w) t += sh_part[w][tid];
    block_part[blockIdx.x * KO + tid] = t;
  }
}

// ---------------------------------------------------------------------------
// kp_pos finalize: reduce 128 block partials per (b,o). 64 threads.
// ---------------------------------------------------------------------------
__global__ __launch_bounds__(64) void kpfinal_k(const float* __restrict__ block_part,
                                                float* __restrict__ out,
                                                float* __restrict__ kp_ws) {
  const int b = blockIdx.x / KO;
  const int o = blockIdx.x % KO;
  const int tid = threadIdx.x;
  float s = block_part[((b << 7) + tid) * KO + o] +
            block_part[((b << 7) + 64 + tid) * KO + o];
#pragma unroll
  for (int m = 1; m < 64; m <<= 1) s += __shfl_xor(s, m, 64);
  if (tid == 0) {
    float v = s * (1.0f / (float)Nn);
    out[b * KO + o] = v;
    kp_ws[b * KO + o] = v;
  }
}

// ---------------------------------------------------------------------------
// dist: thread per point; 48 coalesced reads of voted_t; exp(-d) -> wexp,
// per-(b,k) sums via one atomic per wave-group (tiny, uncontended).
// ---------------------------------------------------------------------------
__global__ __launch_bounds__(256) void dist_k(const float* __restrict__ voted_t,
                                              const float* __restrict__ kp_ws,
                                              float* __restrict__ wexp,
                                              float* __restrict__ wsum) {
  __shared__ float kp[KO];
  __shared__ float red[64];
  const int b = blockIdx.x >> 6;
  const int n0 = (blockIdx.x & 63) * 256;
  const int tid = threadIdx.x;
  if (tid < KO) kp[tid] = kp_ws[b * KO + tid];
  __syncthreads();
  const int n = n0 + tid;
  float e[KK];
#pragma unroll
  for (int k = 0; k < KK; ++k) {
    const float* base = voted_t + (((size_t)b * KO + 3 * k) << 14) + n;
    float dx = base[0] - kp[3 * k];
    float dy = base[1 << 14] - kp[3 * k + 1];
    float dz = base[2 << 14] - kp[3 * k + 2];
    e[k] = __expf(-sqrtf(dx * dx + dy * dy + dz * dz));
    wexp[(((size_t)b * KK + k) << 14) + n] = e[k];
  }
  const int wave = tid >> 6;
  const int lane = tid & 63;
#pragma unroll
  for (int k = 0; k < KK; ++k) {
    float s = e[k];
#pragma unroll
    for (int m = 1; m < 64; m <<= 1) s += __shfl_xor(s, m, 64);
    if (lane == 0) red[wave * KK + k] = s;
  }
  __syncthreads();
  if (tid < KK) {
    float s = red[tid] + red[KK + tid] + red[2 * KK + tid] + red[3 * KK + tid];
    atomicAdd(&wsum[b * KK + tid], s);
  }
}

// ---------------------------------------------------------------------------
// pooling: per-wave partials, NO atomics. Block: 512 pts; wave owns 128 pts;
// lane owns 4 channels. part[blk][wave][k][c] plain coalesced stores.
// ---------------------------------------------------------------------------
__global__ __launch_bounds__(256) void pool_k(const float* __restrict__ ff,
                                              const float* __restrict__ wexp,
                                              const float* __restrict__ wsum,
                                              float* __restrict__ part) {
  __shared__ float wt[512 * 20];   // 40 KB, padded stride 20
  const int b = blockIdx.x >> 5;        // 32 blocks per batch
  const int n0 = (blockIdx.x & 31) * 512;
  const int tid = threadIdx.x;
  float inv[KK];
#pragma unroll
  for (int k = 0; k < KK; ++k) inv[k] = 1.0f / wsum[b * KK + k];
#pragma unroll
  for (int i = 0; i < 2; ++i) {
    int p = i * 256 + tid;
#pragma unroll
    for (int k = 0; k < KK; ++k)
      wt[p * 20 + k] = wexp[(((size_t)b * KK + k) << 14) + n0 + p] * inv[k];
  }
  __syncthreads();
  const int wave = tid >> 6;
  const int lane = tid & 63;
  const float* fp = ff + (size_t)(b * Nn + n0 + wave * 128) * Cc + lane * 4;
  f32x4 acc[KK] = {};
  for (int p = 0; p < 128; ++p) {
    f32x4 f = *reinterpret_cast<const f32x4*>(fp + (size_t)p * Cc);
    const float* wr = &wt[(wave * 128 + p) * 20];
    f32x4 w0 = *reinterpret_cast<const f32x4*>(wr);
    f32x4 w1 = *reinterpret_cast<const f32x4*>(wr + 4);
    f32x4 w2 = *reinterpret_cast<const f32x4*>(wr + 8);
    f32x4 w3 = *reinterpret_cast<const f32x4*>(wr + 12);
#pragma unroll
    for (int j = 0; j < 4; ++j) {
      acc[0 + j] += f * w0[j];
      acc[4 + j] += f * w1[j];
      acc[8 + j] += f * w2[j];
      acc[12 + j] += f * w3[j];
    }
  }
  float* dst = part + (((size_t)blockIdx.x * 4 + wave) << 12) + lane * 4;
#pragma unroll
  for (int k = 0; k < KK; ++k)
    *reinterpret_cast<f32x4*>(dst + (k << 8)) = acc[k];
}

// ---------------------------------------------------------------------------
// keypoint MLP: one block per (b,k); first reduce the 128 pool partials
// (coalesced strided reads), then 3 fp32 layers.
// ---------------------------------------------------------------------------
__global__ __launch_bounds__(256) void mlp_k(
    const float* __restrict__ part,
    const float* __restrict__ Wm1, const float* __restrict__ gm1,
    const float* __restrict__ bm1, const float* __restrict__ mm1,
    const float* __restrict__ vm1,
    const float* __restrict__ Wm2, const float* __restrict__ gm2,
    const float* __restrict__ bm2, const float* __restrict__ mm2,
    const float* __restrict__ vm2,
    const float* __restrict__ Wm3, float* __restrict__ out) {
  __shared__ float xa[256];
  __shared__ float xb[256];
  const int bk = blockIdx.x;
  const int b = bk >> 4;
  const int k = bk & 15;
  const int d = threadIdx.x;
  {
    const float* pp = part + (((size_t)b * 32) << 14) + (k << 8) + d;
    float s = 0.f;
#pragma unroll 4
    for (int j = 0; j < 128; ++j) s += pp[(size_t)j << 12];
    xa[d] = s;
  }
  __syncthreads();
  float acc = 0.f;
  {
    const float4* w4 = reinterpret_cast<const float4*>(Wm1 + d * 256);
    const float4* x4 = reinterpret_cast<const float4*>(xa);
    for (int c = 0; c < 64; ++c) {
      float4 w = w4[c], x = x4[c];
      acc += w.x * x.x + w.y * x.y + w.z * x.z + w.w * x.w;
    }
  }
  {
    float s = gm1[d] * rsqrtf(vm1[d] + EPSBN);
    xb[d] = fmaxf(acc * s + (bm1[d] - mm1[d] * s), 0.f);
  }
  __syncthreads();
  acc = 0.f;
  {
    const float4* w4 = reinterpret_cast<const float4*>(Wm2 + d * 256);
    const float4* x4 = reinterpret_cast<const float4*>(xb);
    for (int c = 0; c < 64; ++c) {
      float4 w = w4[c], x = x4[c];
      acc += w.x * x.x + w.y * x.y + w.z * x.z + w.w * x.w;
    }
  }
  {
    float s = gm2[d] * rsqrtf(vm2[d] + EPSBN);
    xa[d] = fmaxf(acc * s + (bm2[d] - mm2[d] * s), 0.f);
  }
  __syncthreads();
  acc = 0.f;
  {
    const float4* w4 = reinterpret_cast<const float4*>(Wm3 + d * 256);
    const float4* x4 = reinterpret_cast<const float4*>(xa);
    for (int c = 0; c < 64; ++c) {
      float4 w = w4[c], x = x4[c];
      acc += w.x * x.x + w.y * x.y + w.z * x.z + w.w * x.w;
    }
  }
  out[384 + bk * 256 + d] = acc;
}

// ---------------------------------------------------------------------------
// launch
// ---------------------------------------------------------------------------
extern "C" void kernel_launch(void* const* d_in, const int* in_sizes, int n_in,
                              void* d_out, int out_size, void* d_ws, size_t ws_size,
                              hipStream_t stream) {
  const float* ff  = (const float*)d_in[0];
  const float* xyz = (const float*)d_in[1];
  const float* W1 = (const float*)d_in[2];
  const float* g1 = (const float*)d_in[3];
  const float* b1 = (const float*)d_in[4];
  const float* m1 = (const float*)d_in[5];
  const float* v1 = (const float*)d_in[6];
  const float* W2 = (const float*)d_in[7];
  const float* g2 = (const float*)d_in[8];
  const float* b2 = (const float*)d_in[9];
  const float* m2 = (const float*)d_in[10];
  const float* v2 = (const float*)d_in[11];
  const float* W3 = (const float*)d_in[12];
  const float* g3 = (const float*)d_in[13];
  const float* b3 = (const float*)d_in[14];
  const float* m3 = (const float*)d_in[15];
  const float* v3 = (const float*)d_in[16];
  const float* Wo = (const float*)d_in[17];
  const float* bo = (const float*)d_in[18];
  const float* Wm1 = (const float*)d_in[19];
  const float* gm1 = (const float*)d_in[20];
  const float* bm1 = (const float*)d_in[21];
  const float* mm1 = (const float*)d_in[22];
  const float* vm1 = (const float*)d_in[23];
  const float* Wm2 = (const float*)d_in[24];
  const float* gm2 = (const float*)d_in[25];
  const float* bm2 = (const float*)d_in[26];
  const float* mm2 = (const float*)d_in[27];
  const float* vm2 = (const float*)d_in[28];
  const float* Wm3 = (const float*)d_in[29];
  float* out = (float*)d_out;

  char* base = (char*)d_ws;
  size_t off = 0;
  auto carve = [&](size_t bytes) {
    char* p = base + off;
    off = (off + bytes + 511) & ~(size_t)511;
    return p;
  };
  unsigned short* W1b = (unsigned short*)carve(65536 * 2);
  unsigned short* W2b = (unsigned short*)carve(65536 * 2);
  unsigned short* W3b = (unsigned short*)carve(131072 * 2);
  unsigned short* Wob = (unsigned short*)carve(24576 * 2);
  float* st1 = (float*)carve(512 * 4);
  float* st2 = (float*)carve(512 * 4);
  float* st3 = (float*)carve(1024 * 4);
  float* voted_t = (float*)carve((size_t)Bb * KO * Nn * 4);    // 25.2 MB
  float* block_part = (float*)carve((size_t)1024 * KO * 4);
  float* kp_ws = (float*)carve(Bb * KO * 4);
  float* wexp = (float*)carve((size_t)Bb * KK * Nn * 4);       // 8.4 MB
  float* wsum = (float*)carve(Bb * KK * 4);
  float* part = (float*)carve((size_t)256 * 4 * 4096 * 4);     // 16.8 MB
  (void)ws_size; (void)n_in; (void)in_sizes; (void)out_size;

  hipMemsetAsync(wsum, 0, Bb * KK * 4, stream);

  prep_k<<<1120, 256, 0, stream>>>(W1, W2, W3, Wo, g1, b1, m1, v1, g2, b2, m2, v2,
                                   g3, b3, m3, v3, W1b, W2b, W3b, Wob, st1, st2, st3);
  backbone_k<<<1024, 512, 0, stream>>>(ff, xyz, W1b, W2b, W3b, Wob, st1, st2, st3,
                                       bo, voted_t, block_part);
  kpfinal_k<<<Bb * KO, 64, 0, stream>>>(block_part, out, kp_ws);
  dist_k<<<512, 256, 0, stream>>>(voted_t, kp_ws, wexp, wsum);
  pool_k<<<256, 256, 0, stream>>>(ff, wexp, wsum, part);
  mlp_k<<<128, 256, 0, stream>>>(part, Wm1, gm1, bm1, mm1, vm1,
                                 Wm2, gm2, bm2, mm2, vm2, Wm3, out);
}

// Round 6
// 397.121 us; speedup vs baseline: 1.1391x; 1.1391x over previous
//
#include <hip/hip_runtime.h>

// Problem constants
static constexpr int Bb = 8, Nn = 16384, Cc = 256, KO = 48, KK = 16;
#define EPSBN 1e-5f

typedef short bf16x8 __attribute__((ext_vector_type(8)));
typedef float f32x4 __attribute__((ext_vector_type(4)));
typedef unsigned short u16x4 __attribute__((ext_vector_type(4)));

__device__ __forceinline__ unsigned short f2bf(float f) {
  unsigned u = __builtin_bit_cast(unsigned, f);
  u += 0x7FFFu + ((u >> 16) & 1u);   // round-to-nearest-even
  return (unsigned short)(u >> 16);
}

// Blocked LDS layout, 64-pt x 256-ch bf16 tile (round-2 vintage, lowest conflicts):
// element (p, c) at ushort index (c/8)*512 + p*8 + (c%8).
#define LADDR(p, c) ((((c) >> 3) << 9) + ((p) << 3) + ((c) & 7))

// ---------------------------------------------------------------------------
// prep: weights fp32 -> bf16, MFMA-fragment-major swizzle; BN scale/shift;
// zeroes wsum (folded memset).
// Tile (rt, kt) of (16 out-ch x 32 k) = 512 contiguous ushorts:
// lane = (r%16) | ((k%32)/8)<<4 ; j = k%8 ; offset = tile*512 + lane*8 + j.
// ---------------------------------------------------------------------------
__global__ void prep_k(const float* __restrict__ W1, const float* __restrict__ W2,
                       const float* __restrict__ W3, const float* __restrict__ Wo,
                       const float* __restrict__ g1, const float* __restrict__ bb1,
                       const float* __restrict__ m1, const float* __restrict__ v1,
                       const float* __restrict__ g2, const float* __restrict__ bb2,
                       const float* __restrict__ m2, const float* __restrict__ v2,
                       const float* __restrict__ g3, const float* __restrict__ bb3,
                       const float* __restrict__ m3, const float* __restrict__ v3,
                       unsigned short* __restrict__ W1b, unsigned short* __restrict__ W2b,
                       unsigned short* __restrict__ W3b, unsigned short* __restrict__ Wob,
                       float* __restrict__ st1, float* __restrict__ st2,
                       float* __restrict__ st3, float* __restrict__ wsum) {
  int gid = blockIdx.x * 256 + threadIdx.x;
  if (gid < 65536) {
    int r = gid >> 8, k = gid & 255;
    int dst = (((r >> 4) * 8 + (k >> 5)) << 9) + (((r & 15) | (((k >> 3) & 3) << 4)) << 3) + (k & 7);
    W1b[dst] = f2bf(W1[gid]);
  } else if (gid < 131072) {
    int g = gid - 65536;
    int r = g >> 8, k = g & 255;
    int dst = (((r >> 4) * 8 + (k >> 5)) << 9) + (((r & 15) | (((k >> 3) & 3) << 4)) << 3) + (k & 7);
    W2b[dst] = f2bf(W2[g]);
  } else if (gid < 262144) {
    int g = gid - 131072;
    int r = g >> 8, k = g & 255;           // r in [0,512)
    int h = r >> 8, rr = r & 255;
    int dst = h * 65536 + ((((rr >> 4) * 8 + (k >> 5))) << 9) +
              (((rr & 15) | (((k >> 3) & 3) << 4)) << 3) + (k & 7);
    W3b[dst] = f2bf(W3[g]);
  } else if (gid < 286720) {
    int g = gid - 262144;
    int r = g >> 9, k = g & 511;           // Wo is 48 x 512
    int dst = (((r >> 4) * 16 + (k >> 5)) << 9) + (((r & 15) | (((k >> 3) & 3) << 4)) << 3) + (k & 7);
    Wob[dst] = f2bf(Wo[g]);
  }
  if (gid < 256) {
    float s = g1[gid] * rsqrtf(v1[gid] + EPSBN);
    st1[2 * gid] = s; st1[2 * gid + 1] = bb1[gid] - m1[gid] * s;
  } else if (gid < 512) {
    int i = gid - 256;
    float s = g2[i] * rsqrtf(v2[i] + EPSBN);
    st2[2 * i] = s; st2[2 * i + 1] = bb2[i] - m2[i] * s;
  } else if (gid < 1024) {
    int i = gid - 512;
    float s = g3[i] * rsqrtf(v3[i] + EPSBN);
    st3[2 * i] = s; st3[2 * i + 1] = bb3[i] - m3[i] * s;
  } else if (gid < 1024 + Bb * KK) {
    wsum[gid - 1024] = 0.f;
  }
}

// ---------------------------------------------------------------------------
// backbone: 256 threads (4 waves), 64 points/block, 2 blocks/CU.
// Wave owns 64 out-ch x 64 pts. Quarter-K software pipeline: each quarter
// (2 kb-steps) loads 8 A-frags (global, swizzled) + 8 B-frags (LDS) into a
// 2-deep ring; sched_barrier(0) pins next-quarter loads before this
// quarter's MFMA burst so the compiler cannot sink/merge the ring.
// ---------------------------------------------------------------------------
__device__ __forceinline__ void gemm64(const unsigned short* __restrict__ src,
                                       unsigned short* __restrict__ dst,
                                       const unsigned short* __restrict__ Wsw,
                                       const float* __restrict__ st, int tid) {
  const int lane = tid & 63;
  const int cg = tid >> 6;        // wave = ch-group (64 ch)
  const int ln15 = lane & 15;
  const int q = lane >> 4;
  f32x4 acc[4][4] = {};
  const unsigned short* wb = Wsw + ((cg * 32) << 9) + lane * 8;  // tiles (cg*4+ct)*8+kb

  bf16x8 A[2][8], Bf[2][8];
#pragma unroll
  for (int ct = 0; ct < 4; ++ct)
#pragma unroll
    for (int k2 = 0; k2 < 2; ++k2)
      A[0][ct * 2 + k2] = *reinterpret_cast<const bf16x8*>(wb + ((ct * 8 + k2) << 9));
#pragma unroll
  for (int pt = 0; pt < 4; ++pt)
#pragma unroll
    for (int k2 = 0; k2 < 2; ++k2)
      Bf[0][pt * 2 + k2] = *reinterpret_cast<const bf16x8*>(
          &src[((k2 * 4 + q) << 9) + ((pt * 16 + ln15) << 3)]);

#pragma unroll
  for (int h = 0; h < 4; ++h) {
    const int cur = h & 1, nxt = cur ^ 1;
    if (h < 3) {
      const int kb0 = (h + 1) * 2;
#pragma unroll
      for (int ct = 0; ct < 4; ++ct)
#pragma unroll
        for (int k2 = 0; k2 < 2; ++k2)
          A[nxt][ct * 2 + k2] = *reinterpret_cast<const bf16x8*>(wb + ((ct * 8 + kb0 + k2) << 9));
#pragma unroll
      for (int pt = 0; pt < 4; ++pt)
#pragma unroll
        for (int k2 = 0; k2 < 2; ++k2)
          Bf[nxt][pt * 2 + k2] = *reinterpret_cast<const bf16x8*>(
              &src[(((kb0 + k2) * 4 + q) << 9) + ((pt * 16 + ln15) << 3)]);
    }
    __builtin_amdgcn_sched_barrier(0);   // loads above may not sink below
#pragma unroll
    for (int k2 = 0; k2 < 2; ++k2)
#pragma unroll
      for (int ct = 0; ct < 4; ++ct)
#pragma unroll
        for (int pt = 0; pt < 4; ++pt)
          acc[ct][pt] = __builtin_amdgcn_mfma_f32_16x16x32_bf16(
              A[cur][ct * 2 + k2], Bf[cur][pt * 2 + k2], acc[ct][pt], 0, 0, 0);
  }

  // epilogue: BN + ReLU, fp32 -> bf16, blocked LDS write
#pragma unroll
  for (int ct = 0; ct < 4; ++ct) {
    const int chl = cg * 64 + ct * 16 + q * 4;
    float s0[4], t0[4];
#pragma unroll
    for (int r = 0; r < 4; ++r) {
      s0[r] = st[2 * (chl + r)];
      t0[r] = st[2 * (chl + r) + 1];
    }
#pragma unroll
    for (int pt = 0; pt < 4; ++pt) {
      const int p = pt * 16 + ln15;
      u16x4 hv;
#pragma unroll
      for (int r = 0; r < 4; ++r) {
        float v = fmaxf(acc[ct][pt][r] * s0[r] + t0[r], 0.f);
        hv[r] = f2bf(v);
      }
      *reinterpret_cast<u16x4*>(&dst[LADDR(p, chl)]) = hv;
    }
  }
}

// Wo partial: wave owns 16 points (4 waves x 16 = 64), all 48 output rows.
__device__ __forceinline__ void wo64(const unsigned short* __restrict__ src,
                                     const unsigned short* __restrict__ Wosw,
                                     int h, f32x4* accO, int tid) {
  const int lane = tid & 63;
  const int wave = tid >> 6;
  const int ln15 = lane & 15;
  const int q = lane >> 4;
#pragma unroll
  for (int kb = 0; kb < 8; ++kb) {
    bf16x8 bfr = *reinterpret_cast<const bf16x8*>(
        &src[((kb * 4 + q) << 9) + ((wave * 16 + ln15) << 3)]);
#pragma unroll
    for (int ot = 0; ot < 3; ++ot) {
      bf16x8 afr = *reinterpret_cast<const bf16x8*>(&Wosw[((ot * 16 + 8 * h + kb) << 9) + lane * 8]);
      accO[ot] = __builtin_amdgcn_mfma_f32_16x16x32_bf16(afr, bfr, accO[ot], 0, 0, 0);
    }
  }
}

__global__ __launch_bounds__(256, 2) void backbone_k(
    const float* __restrict__ ff, const float* __restrict__ xyz,
    const unsigned short* __restrict__ W1b, const unsigned short* __restrict__ W2b,
    const unsigned short* __restrict__ W3b, const unsigned short* __restrict__ Wob,
    const float* __restrict__ st1, const float* __restrict__ st2,
    const float* __restrict__ st3, const float* __restrict__ bo,
    float* __restrict__ voted_t, float* __restrict__ block_part) {
  __shared__ unsigned short bufA[64 * 256];   // 32 KB
  __shared__ unsigned short bufB[64 * 256];   // 32 KB
  __shared__ float sh_part[4][KO];
  const int tid = threadIdx.x;
  const int b = blockIdx.x >> 8;
  const int n0 = (blockIdx.x & 255) * 64;
  const int lane = tid & 63;
  const int wave = tid >> 6;

  // stage ff tile -> bufA (bf16, blocked layout)
  {
    const float* src = ff + (size_t)(b * Nn + n0) * Cc;
#pragma unroll
    for (int i = 0; i < 16; ++i) {
      int p = (tid & 15) + 16 * (i & 3);
      int c4 = (tid >> 4) + 16 * (i >> 2);
      const float4 v = *reinterpret_cast<const float4*>(src + p * Cc + c4 * 4);
      u16x4 h;
      h.x = f2bf(v.x); h.y = f2bf(v.y); h.z = f2bf(v.z); h.w = f2bf(v.w);
      *reinterpret_cast<u16x4*>(&bufA[LADDR(p, c4 * 4)]) = h;
    }
  }
  __syncthreads();

  gemm64(bufA, bufB, W1b, st1, tid);
  __syncthreads();
  gemm64(bufB, bufA, W2b, st2, tid);
  __syncthreads();
  gemm64(bufA, bufB, W3b, st3, tid);
  __syncthreads();

  f32x4 accO[3] = {};
  wo64(bufB, Wob, 0, accO, tid);
  __syncthreads();
  gemm64(bufA, bufB, W3b + 65536, st3 + 512, tid);
  __syncthreads();
  wo64(bufB, Wob, 1, accO, tid);

  // epilogue: voted (transposed [b][o][n]) + block partial sums
  const int ln15 = lane & 15;
  const int q = lane >> 4;
  const int p = wave * 16 + ln15;
  const int n = n0 + p;
  const float* xp = xyz + (size_t)(b * Nn + n) * 3;
  float xv[3] = {xp[0], xp[1], xp[2]};
#pragma unroll
  for (int ot = 0; ot < 3; ++ot) {
#pragma unroll
    for (int r = 0; r < 4; ++r) {
      int o = ot * 16 + q * 4 + r;  // o = k*3 + d
      float v = accO[ot][r] + bo[o] + xv[o % 3];
      voted_t[(((size_t)b * KO + o) << 14) + n] = v;
      float s = v;
      s += __shfl_xor(s, 1, 64);
      s += __shfl_xor(s, 2, 64);
      s += __shfl_xor(s, 4, 64);
      s += __shfl_xor(s, 8, 64);
      if (ln15 == 0) sh_part[wave][o] = s;
    }
  }
  __syncthreads();
  if (tid < KO) {
    float t = sh_part[0][tid] + sh_part[1][tid] + sh_part[2][tid] + sh_part[3][tid];
    block_part[blockIdx.x * KO + tid] = t;
  }
}

// ---------------------------------------------------------------------------
// dist (+ fused kp finalize): each block reduces its batch's 256 block
// partials to kp (48 KB L2 read), then computes exp(-dist) per point.
// ---------------------------------------------------------------------------
__global__ __launch_bounds__(256) void dist_k(const float* __restrict__ block_part,
                                              const float* __restrict__ voted_t,
                                              float* __restrict__ out,
                                              float* __restrict__ wexp,
                                              float* __restrict__ wsum) {
  __shared__ float kp[KO];
  __shared__ float sh[4][KO];
  __shared__ float red[64];
  const int b = blockIdx.x >> 6;
  const int n0 = (blockIdx.x & 63) * 256;
  const int tid = threadIdx.x;
  if (tid < 192) {
    int o = tid % KO, c = tid / KO;
    const float* bp = block_part + ((size_t)b * 256 + c * 64) * KO + o;
    float s = 0.f;
#pragma unroll 8
    for (int j = 0; j < 64; ++j) s += bp[j * KO];
    sh[c][o] = s;
  }
  __syncthreads();
  if (tid < KO) {
    float v = (sh[0][tid] + sh[1][tid] + sh[2][tid] + sh[3][tid]) * (1.0f / (float)Nn);
    kp[tid] = v;
    if ((blockIdx.x & 63) == 0) out[b * KO + tid] = v;
  }
  __syncthreads();
  const int n = n0 + tid;
  float e[KK];
#pragma unroll
  for (int k = 0; k < KK; ++k) {
    const float* base = voted_t + (((size_t)b * KO + 3 * k) << 14) + n;
    float dx = base[0] - kp[3 * k];
    float dy = base[1 << 14] - kp[3 * k + 1];
    float dz = base[2 << 14] - kp[3 * k + 2];
    e[k] = __expf(-sqrtf(dx * dx + dy * dy + dz * dz));
    wexp[(((size_t)b * KK + k) << 14) + n] = e[k];
  }
  const int wave = tid >> 6;
  const int lane = tid & 63;
#pragma unroll
  for (int k = 0; k < KK; ++k) {
    float s = e[k];
#pragma unroll
    for (int m = 1; m < 64; m <<= 1) s += __shfl_xor(s, m, 64);
    if (lane == 0) red[wave * KK + k] = s;
  }
  __syncthreads();
  if (tid < KK) {
    float s = red[tid] + red[KK + tid] + red[2 * KK + tid] + red[3 * KK + tid];
    atomicAdd(&wsum[b * KK + tid], s);
  }
}

// ---------------------------------------------------------------------------
// pooling: per-wave partials, NO atomics. Block: 512 pts; wave owns 128 pts;
// lane owns 4 channels. part[blk][wave][k][c] plain coalesced stores.
// ---------------------------------------------------------------------------
__global__ __launch_bounds__(256) void pool_k(const float* __restrict__ ff,
                                              const float* __restrict__ wexp,
                                              const float* __restrict__ wsum,
                                              float* __restrict__ part) {
  __shared__ float wt[512 * 20];   // 40 KB, padded stride 20
  const int b = blockIdx.x >> 5;        // 32 blocks per batch
  const int n0 = (blockIdx.x & 31) * 512;
  const int tid = threadIdx.x;
  float inv[KK];
#pragma unroll
  for (int k = 0; k < KK; ++k) inv[k] = 1.0f / wsum[b * KK + k];
#pragma unroll
  for (int i = 0; i < 2; ++i) {
    int p = i * 256 + tid;
#pragma unroll
    for (int k = 0; k < KK; ++k)
      wt[p * 20 + k] = wexp[(((size_t)b * KK + k) << 14) + n0 + p] * inv[k];
  }
  __syncthreads();
  const int wave = tid >> 6;
  const int lane = tid & 63;
  const float* fp = ff + (size_t)(b * Nn + n0 + wave * 128) * Cc + lane * 4;
  f32x4 acc[KK] = {};
  for (int p = 0; p < 128; ++p) {
    f32x4 f = *reinterpret_cast<const f32x4*>(fp + (size_t)p * Cc);
    const float* wr = &wt[(wave * 128 + p) * 20];
    f32x4 w0 = *reinterpret_cast<const f32x4*>(wr);
    f32x4 w1 = *reinterpret_cast<const f32x4*>(wr + 4);
    f32x4 w2 = *reinterpret_cast<const f32x4*>(wr + 8);
    f32x4 w3 = *reinterpret_cast<const f32x4*>(wr + 12);
#pragma unroll
    for (int j = 0; j < 4; ++j) {
      acc[0 + j] += f * w0[j];
      acc[4 + j] += f * w1[j];
      acc[8 + j] += f * w2[j];
      acc[12 + j] += f * w3[j];
    }
  }
  float* dst = part + (((size_t)blockIdx.x * 4 + wave) << 12) + lane * 4;
#pragma unroll
  for (int k = 0; k < KK; ++k)
    *reinterpret_cast<f32x4*>(dst + (k << 8)) = acc[k];
}

// ---------------------------------------------------------------------------
// keypoint MLP: one block per (b,k); reduce 128 pool partials, then 3 layers.
// ---------------------------------------------------------------------------
__global__ __launch_bounds__(256) void mlp_k(
    const float* __restrict__ part,
    const float* __restrict__ Wm1, const float* __restrict__ gm1,
    const float* __restrict__ bm1, const float* __restrict__ mm1,
    const float* __restrict__ vm1,
    const float* __restrict__ Wm2, const float* __restrict__ gm2,
    const float* __restrict__ bm2, const float* __restrict__ mm2,
    const float* __restrict__ vm2,
    const float* __restrict__ Wm3, float* __restrict__ out) {
  __shared__ float xa[256];
  __shared__ float xb[256];
  const int bk = blockIdx.x;
  const int b = bk >> 4;
  const int k = bk & 15;
  const int d = threadIdx.x;
  {
    const float* pp = part + (((size_t)b * 32) << 14) + (k << 8) + d;
    float s = 0.f;
#pragma unroll 4
    for (int j = 0; j < 128; ++j) s += pp[(size_t)j << 12];
    xa[d] = s;
  }
  __syncthreads();
  float acc = 0.f;
  {
    const float4* w4 = reinterpret_cast<const float4*>(Wm1 + d * 256);
    const float4* x4 = reinterpret_cast<const float4*>(xa);
    for (int c = 0; c < 64; ++c) {
      float4 w = w4[c], x = x4[c];
      acc += w.x * x.x + w.y * x.y + w.z * x.z + w.w * x.w;
    }
  }
  {
    float s = gm1[d] * rsqrtf(vm1[d] + EPSBN);
    xb[d] = fmaxf(acc * s + (bm1[d] - mm1[d] * s), 0.f);
  }
  __syncthreads();
  acc = 0.f;
  {
    const float4* w4 = reinterpret_cast<const float4*>(Wm2 + d * 256);
    const float4* x4 = reinterpret_cast<const float4*>(xb);
    for (int c = 0; c < 64; ++c) {
      float4 w = w4[c], x = x4[c];
      acc += w.x * x.x + w.y * x.y + w.z * x.z + w.w * x.w;
    }
  }
  {
    float s = gm2[d] * rsqrtf(vm2[d] + EPSBN);
    xa[d] = fmaxf(acc * s + (bm2[d] - mm2[d] * s), 0.f);
  }
  __syncthreads();
  acc = 0.f;
  {
    const float4* w4 = reinterpret_cast<const float4*>(Wm3 + d * 256);
    const float4* x4 = reinterpret_cast<const float4*>(xa);
    for (int c = 0; c < 64; ++c) {
      float4 w = w4[c], x = x4[c];
      acc += w.x * x.x + w.y * x.y + w.z * x.z + w.w * x.w;
    }
  }
  out[384 + bk * 256 + d] = acc;
}

// ---------------------------------------------------------------------------
// launch (5 dispatches, no memsets)
// ---------------------------------------------------------------------------
extern "C" void kernel_launch(void* const* d_in, const int* in_sizes, int n_in,
                              void* d_out, int out_size, void* d_ws, size_t ws_size,
                              hipStream_t stream) {
  const float* ff  = (const float*)d_in[0];
  const float* xyz = (const float*)d_in[1];
  const float* W1 = (const float*)d_in[2];
  const float* g1 = (const float*)d_in[3];
  const float* b1 = (const float*)d_in[4];
  const float* m1 = (const float*)d_in[5];
  const float* v1 = (const float*)d_in[6];
  const float* W2 = (const float*)d_in[7];
  const float* g2 = (const float*)d_in[8];
  const float* b2 = (const float*)d_in[9];
  const float* m2 = (const float*)d_in[10];
  const float* v2 = (const float*)d_in[11];
  const float* W3 = (const float*)d_in[12];
  const float* g3 = (const float*)d_in[13];
  const float* b3 = (const float*)d_in[14];
  const float* m3 = (const float*)d_in[15];
  const float* v3 = (const float*)d_in[16];
  const float* Wo = (const float*)d_in[17];
  const float* bo = (const float*)d_in[18];
  const float* Wm1 = (const float*)d_in[19];
  const float* gm1 = (const float*)d_in[20];
  const float* bm1 = (const float*)d_in[21];
  const float* mm1 = (const float*)d_in[22];
  const float* vm1 = (const float*)d_in[23];
  const float* Wm2 = (const float*)d_in[24];
  const float* gm2 = (const float*)d_in[25];
  const float* bm2 = (const float*)d_in[26];
  const float* mm2 = (const float*)d_in[27];
  const float* vm2 = (const float*)d_in[28];
  const float* Wm3 = (const float*)d_in[29];
  float* out = (float*)d_out;

  char* base = (char*)d_ws;
  size_t off = 0;
  auto carve = [&](size_t bytes) {
    char* p = base + off;
    off = (off + bytes + 511) & ~(size_t)511;
    return p;
  };
  unsigned short* W1b = (unsigned short*)carve(65536 * 2);
  unsigned short* W2b = (unsigned short*)carve(65536 * 2);
  unsigned short* W3b = (unsigned short*)carve(131072 * 2);
  unsigned short* Wob = (unsigned short*)carve(24576 * 2);
  float* st1 = (float*)carve(512 * 4);
  float* st2 = (float*)carve(512 * 4);
  float* st3 = (float*)carve(1024 * 4);
  float* voted_t = (float*)carve((size_t)Bb * KO * Nn * 4);    // 25.2 MB
  float* block_part = (float*)carve((size_t)2048 * KO * 4);    // 393 KB
  float* wexp = (float*)carve((size_t)Bb * KK * Nn * 4);       // 8.4 MB
  float* wsum = (float*)carve(Bb * KK * 4);
  float* part = (float*)carve((size_t)256 * 4 * 4096 * 4);     // 16.8 MB
  (void)ws_size; (void)n_in; (void)in_sizes; (void)out_size;

  prep_k<<<1120, 256, 0, stream>>>(W1, W2, W3, Wo, g1, b1, m1, v1, g2, b2, m2, v2,
                                   g3, b3, m3, v3, W1b, W2b, W3b, Wob, st1, st2, st3,
                                   wsum);
  backbone_k<<<2048, 256, 0, stream>>>(ff, xyz, W1b, W2b, W3b, Wob, st1, st2, st3,
                                       bo, voted_t, block_part);
  dist_k<<<512, 256, 0, stream>>>(block_part, voted_t, out, wexp, wsum);
  pool_k<<<256, 256, 0, stream>>>(ff, wexp, wsum, part);
  mlp_k<<<128, 256, 0, stream>>>(part, Wm1, gm1, bm1, mm1, vm1,
                                 Wm2, gm2, bm2, mm2, vm2, Wm3, out);
}